// Round 5
// baseline (190.270 us; speedup 1.0000x reference)
//
#include <hip/hip_runtime.h>
#include <cstdint>
#include <cstddef>

#define NHEAD 8
#define HDIM 32
#define DMODEL 256
#define NLEVEL 4
#define NPOINT 4

// ---------------------------------------------------------------------------
// f32 GEMM: C(M,N) = A(M,K) @ Bm(N,K)^T + bias(N), optional row-mask zeroing.
// BM=BN=64, BK=16, 256 threads, 4x4 microtile, double-buffered LDS with
// register prefetch, ONE barrier per K-step. Grid ~964 blocks -> ~4 blocks/CU
// -> 100% occupancy (16.6 KB LDS, ~40 VGPR): latency hidden by TLP.
// blockIdx.z selects weight/bias/output set (fuses the two logits GEMMs).
// ---------------------------------------------------------------------------
#define OUTER(ACC, BV, a) { (ACC).x += (a)*(BV).x; (ACC).y += (a)*(BV).y; \
                            (ACC).z += (a)*(BV).z; (ACC).w += (a)*(BV).w; }

template<int ID>
__global__ __launch_bounds__(256) void gemm_bt(
    const float* __restrict__ A,
    const float* __restrict__ B0, const float* __restrict__ bias0, float* __restrict__ C0,
    const float* __restrict__ B1, const float* __restrict__ bias1, float* __restrict__ C1,
    const unsigned char* __restrict__ maskp,
    int M, int N, int K)
{
    constexpr int BM = 64, BN = 64, BK = 16;
    __shared__ float As[2][BK][BM + 1];   // +1: conflict-free column writes
    __shared__ float Bs[2][BK][BN + 1];

    const float* Bm   = blockIdx.z ? B1 : B0;
    const float* bias = blockIdx.z ? bias1 : bias0;
    float*       C    = blockIdx.z ? C1 : C0;

    const int row0 = blockIdx.y * BM;
    const int col0 = blockIdx.x * BN;
    const int tid  = threadIdx.x;

    // staging map: thread -> row sr (0..63), k-quad sk (0,4,8,12); coalesced float4
    const int sr = tid >> 2;
    const int sk = (tid & 3) << 2;
    // compute map: 4x4 microtile
    const int tm = ((tid >> 4) & 15) << 2;  // 0..60
    const int tn = (tid & 15) << 2;         // 0..60

    const bool aok = (row0 + sr) < M;
    const float* aptr = A  + (size_t)(row0 + sr) * K + sk;
    const float* bptr = Bm + (size_t)(col0 + sr) * K + sk;

    float4 acc[4];
#pragma unroll
    for (int i = 0; i < 4; i++) acc[i] = make_float4(0.f, 0.f, 0.f, 0.f);

    // prefetch tile 0
    float4 pa = make_float4(0.f, 0.f, 0.f, 0.f);
    float4 pb;
    if (aok) pa = *(const float4*)aptr;
    pb = *(const float4*)bptr;

    int buf = 0;
    for (int kb = 0; kb < K; kb += BK) {
        // commit prefetched regs to LDS[buf]
        As[buf][sk + 0][sr] = pa.x; As[buf][sk + 1][sr] = pa.y;
        As[buf][sk + 2][sr] = pa.z; As[buf][sk + 3][sr] = pa.w;
        Bs[buf][sk + 0][sr] = pb.x; Bs[buf][sk + 1][sr] = pb.y;
        Bs[buf][sk + 2][sr] = pb.z; Bs[buf][sk + 3][sr] = pb.w;
        __syncthreads();   // single barrier per K-step (write->read hand-off)

        // issue next tile's global loads; latency hidden under compute below
        if (kb + BK < K) {
            if (aok) pa = *(const float4*)(aptr + kb + BK);
            pb = *(const float4*)(bptr + kb + BK);
        }

#pragma unroll
        for (int k = 0; k < BK; ++k) {
            const float4 av = *(const float4*)&As[buf][k][tm];
            const float4 bv = *(const float4*)&Bs[buf][k][tn];
            OUTER(acc[0], bv, av.x);
            OUTER(acc[1], bv, av.y);
            OUTER(acc[2], bv, av.z);
            OUTER(acc[3], bv, av.w);
        }
        buf ^= 1;
    }

    // --- epilogue: bias, optional mask zero, vectorized store ---
    const float4 bv = *(const float4*)(bias + col0 + tn);
#pragma unroll
    for (int i = 0; i < 4; i++) {
        const int row = row0 + tm + i;
        if (row >= M) continue;
        float4 o = acc[i];
        o.x += bv.x; o.y += bv.y; o.z += bv.z; o.w += bv.w;
        if (maskp && maskp[row]) o = make_float4(0.f, 0.f, 0.f, 0.f);
        *(float4*)(C + (size_t)row * N + col0 + tn) = o;
    }
}

// ---------------------------------------------------------------------------
// Box-attention sampling, two-phase (unchanged from R4: 53.7us control):
//   phase 1 (128 threads): 4 rows x 8 heads x 4 levels -> clamped indices +
//            combined weights (softmax * bilinear * validity) into LDS
//   phase 2 (256 threads): pure gather+FMA; 8 float4-lanes x 8 heads x 4 rows
// ---------------------------------------------------------------------------
#define ROWS 4
#define PP 17   // padded point dim

__global__ __launch_bounds__(256) void box_sample(
    const float* __restrict__ v,      // (B*L2, 256) projected+masked value
    const float* __restrict__ alog,   // (B*L1, 128) attn logits (h,l,p)
    const float* __restrict__ blg,    // (B*L1, 128) box logits (h,l,4)
    const float* __restrict__ rwin,   // (B*L1, 4)
    const float* __restrict__ vratio, // (B, NLEVEL, 2)
    float* __restrict__ outp,         // (B*L1, 256)
    int M1, int L1, int L2)
{
    __shared__ int   s_idx[ROWS][NHEAD][PP][4];
    __shared__ float s_w  [ROWS][NHEAD][PP][4];

    const int row0 = blockIdx.x * ROWS;
    const int tid  = threadIdx.x;

    // ================= phase 1 =================
    if (tid < 128) {
        const int l = tid & 3;
        const int h = (tid >> 2) & 7;
        const int r = tid >> 5;             // 0..3
        const int rowq = row0 + r;
        if (rowq < M1) {
            const int b = (rowq >= L1) ? 1 : 0;
            float la[16];
            const float* al = alog + (size_t)rowq * 128 + h * 16;
            {
                const float4 q0 = *(const float4*)(al + 0);
                const float4 q1 = *(const float4*)(al + 4);
                const float4 q2 = *(const float4*)(al + 8);
                const float4 q3 = *(const float4*)(al + 12);
                la[0]=q0.x; la[1]=q0.y; la[2]=q0.z; la[3]=q0.w;
                la[4]=q1.x; la[5]=q1.y; la[6]=q1.z; la[7]=q1.w;
                la[8]=q2.x; la[9]=q2.y; la[10]=q2.z; la[11]=q2.w;
                la[12]=q3.x; la[13]=q3.y; la[14]=q3.z; la[15]=q3.w;
            }
            float m = la[0];
#pragma unroll
            for (int i = 1; i < 16; i++) m = fmaxf(m, la[i]);
            float s = 0.f;
#pragma unroll
            for (int i = 0; i < 16; i++) { la[i] = __expf(la[i] - m); s += la[i]; }
            const float inv = 1.f / s;

            const int H  = (l == 0) ? 76 : (l == 1) ? 38 : (l == 2) ? 19 : 10;
            const int W  = H;
            const int s0 = (l == 0) ? 0  : (l == 1) ? 5776 : (l == 2) ? 7220 : 7581;

            const float4 ob = *(const float4*)(blg + (size_t)rowq * 128 + h * 16 + l * 4);
            const float4 rw = *(const float4*)(rwin + (size_t)rowq * 4);
            const float vrx = vratio[(b * NLEVEL + l) * 2 + 0];
            const float vry = vratio[(b * NLEVEL + l) * 2 + 1];

            const float cx = rw.x + ob.x * 0.125f * rw.z;
            const float cy = rw.y + ob.y * 0.125f * rw.w;
            const float sw = fmaxf(rw.z + ob.z * 0.125f * rw.z, 0.f);
            const float sh = fmaxf(rw.w + ob.w * 0.125f * rw.w, 0.f);

            const int vbase = (b * L2 + s0) * DMODEL + h * HDIM;

#pragma unroll
            for (int p = 0; p < 4; ++p) {
                const float kx = (p & 1)  ? 0.25f : -0.25f;
                const float ky = (p >> 1) ? 0.25f : -0.25f;
                const float gx = (cx + kx * sw) * vrx;
                const float gy = (cy + ky * sh) * vry;
                const float x = gx * (float)W - 0.5f;
                const float y = gy * (float)H - 0.5f;
                const float x0f = floorf(x);
                const float y0f = floorf(y);
                const float lx = x - x0f, ly = y - y0f;
                const int x0 = (int)x0f, y0 = (int)y0f;
                const float aw = la[l * 4 + p] * inv;
                const float wb[4] = { (1.f - ly) * (1.f - lx) * aw,
                                      (1.f - ly) * lx * aw,
                                      ly * (1.f - lx) * aw,
                                      ly * lx * aw };
                const int lp = l * 4 + p;
#pragma unroll
                for (int j = 0; j < 4; ++j) {
                    const int yy = y0 + (j >> 1);
                    const int xx = x0 + (j & 1);
                    const bool ok = (yy >= 0) & (yy < H) & (xx >= 0) & (xx < W);
                    const int yc = min(max(yy, 0), H - 1);
                    const int xc = min(max(xx, 0), W - 1);
                    s_idx[r][h][lp][j] = vbase + (yc * W + xc) * DMODEL;
                    s_w  [r][h][lp][j] = ok ? wb[j] : 0.f;
                }
            }
        }
    }
    __syncthreads();

    // ================= phase 2 =================
    {
        const int c4 = (tid & 7) << 2;      // channel quad: 0..28
        const int h  = (tid >> 3) & 7;
        const int r  = tid >> 6;            // 0..3
        const int rowq = row0 + r;
        if (rowq < M1) {
            float4 acc = make_float4(0.f, 0.f, 0.f, 0.f);
#pragma unroll 4
            for (int p = 0; p < 16; ++p) {
                const int4   iv = *(const int4  *)&s_idx[r][h][p][0];
                const float4 wv = *(const float4*)&s_w  [r][h][p][0];
                const float4 g0 = *(const float4*)(v + iv.x + c4);
                const float4 g1 = *(const float4*)(v + iv.y + c4);
                const float4 g2 = *(const float4*)(v + iv.z + c4);
                const float4 g3 = *(const float4*)(v + iv.w + c4);
                acc.x += wv.x*g0.x; acc.y += wv.x*g0.y; acc.z += wv.x*g0.z; acc.w += wv.x*g0.w;
                acc.x += wv.y*g1.x; acc.y += wv.y*g1.y; acc.z += wv.y*g1.z; acc.w += wv.y*g1.w;
                acc.x += wv.z*g2.x; acc.y += wv.z*g2.y; acc.z += wv.z*g2.z; acc.w += wv.z*g2.w;
                acc.x += wv.w*g3.x; acc.y += wv.w*g3.y; acc.z += wv.w*g3.z; acc.w += wv.w*g3.w;
            }
            *(float4*)(outp + (size_t)rowq * DMODEL + h * HDIM + c4) = acc;
        }
    }
}

// ---------------------------------------------------------------------------
extern "C" void kernel_launch(void* const* d_in, const int* in_sizes, int n_in,
                              void* d_out, int out_size, void* d_ws, size_t ws_size,
                              hipStream_t stream) {
    const float* query   = (const float*)d_in[0];
    const float* value   = (const float*)d_in[1];
    const unsigned char* v_mask = (const unsigned char*)d_in[3];
    const float* v_valid = (const float*)d_in[5];
    const float* ref_win = (const float*)d_in[6];
    const float* vproj_w = (const float*)d_in[7];
    const float* vproj_b = (const float*)d_in[8];
    const float* oproj_w = (const float*)d_in[9];
    const float* oproj_b = (const float*)d_in[10];
    const float* box_w   = (const float*)d_in[11];
    const float* box_b   = (const float*)d_in[12];
    const float* attn_w  = (const float*)d_in[13];
    const float* attn_b  = (const float*)d_in[14];

    const int B  = 2;
    const int M1 = in_sizes[0] / DMODEL;   // B*L1
    const int M2 = in_sizes[1] / DMODEL;   // B*L2
    const int L1 = M1 / B;
    const int L2 = M2 / B;

    float* ws    = (float*)d_ws;
    float* vproj = ws;                                  // M2*256
    float* alog  = vproj + (size_t)M2 * DMODEL;         // M1*128
    float* blg   = alog  + (size_t)M1 * 128;            // M1*128
    float* outp  = blg   + (size_t)M1 * 128;            // M1*256

    const dim3 blk(256);
    const int mb1 = (M1 + 63) / 64;
    const int mb2 = (M2 + 63) / 64;

    // 1) value projection (+mask zeroing fused)
    gemm_bt<0><<<dim3(4, mb2, 1), blk, 0, stream>>>(
        value, vproj_w, vproj_b, vproj, vproj_w, vproj_b, vproj,
        v_mask, M2, DMODEL, DMODEL);

    // 2) attn + box logits in one launch (blockIdx.z selects the set)
    gemm_bt<1><<<dim3(2, mb1, 2), blk, 0, stream>>>(
        query, attn_w, attn_b, alog, box_w, box_b, blg,
        nullptr, M1, 128, DMODEL);

    // 3) sampling
    box_sample<<<dim3((M1 + ROWS - 1) / ROWS), blk, 0, stream>>>(
        vproj, alog, blg, ref_win, v_valid, outp, M1, L1, L2);

    // 4) output projection
    gemm_bt<2><<<dim3(4, mb1, 1), blk, 0, stream>>>(
        outp, oproj_w, oproj_b, (float*)d_out, oproj_w, oproj_b, (float*)d_out,
        nullptr, M1, DMODEL, DMODEL);
}

// Round 7
// 155.446 us; speedup vs baseline: 1.2240x; 1.2240x over previous
//
#include <hip/hip_runtime.h>
#include <cstdint>
#include <cstddef>

#define NHEAD 8
#define HDIM 32
#define DMODEL 256
#define NLEVEL 4
#define NPOINT 4

// ---------------------------------------------------------------------------
// f32 GEMM: C(M,N) = A(M,K) @ Bm(N,K)^T + bias(N), optional row-mask zeroing.
// BM=BN=64, BK=16, 256 threads, 4x4 microtile, double-buffered LDS with
// register prefetch, ONE barrier per K-step. Grid ~964 blocks -> ~4 blocks/CU.
// LDS rows UNPADDED: row stride 64 floats keeps every float4 16B-aligned so
// the compiler emits ds_read_b128 (R5's +1 pad scalarized reads -> 36% regress).
// Read conflicts without pad: av = 4 unique addrs/wave (broadcast, free),
// bv = 2-way alias (free per m136).
// blockIdx.z selects weight/bias/output set (fuses the two logits GEMMs).
// ---------------------------------------------------------------------------
#define OUTER(ACC, BV, a) { (ACC).x += (a)*(BV).x; (ACC).y += (a)*(BV).y; \
                            (ACC).z += (a)*(BV).z; (ACC).w += (a)*(BV).w; }

template<int ID>
__global__ __launch_bounds__(256) void gemm_bt(
    const float* __restrict__ A,
    const float* __restrict__ B0, const float* __restrict__ bias0, float* __restrict__ C0,
    const float* __restrict__ B1, const float* __restrict__ bias1, float* __restrict__ C1,
    const unsigned char* __restrict__ maskp,
    int M, int N, int K)
{
    constexpr int BM = 64, BN = 64, BK = 16;
    __shared__ float As[2][BK][BM];
    __shared__ float Bs[2][BK][BN];

    const float* Bm   = blockIdx.z ? B1 : B0;
    const float* bias = blockIdx.z ? bias1 : bias0;
    float*       C    = blockIdx.z ? C1 : C0;

    const int row0 = blockIdx.y * BM;
    const int col0 = blockIdx.x * BN;
    const int tid  = threadIdx.x;

    // staging map: thread -> row sr (0..63), k-quad sk (0,4,8,12); coalesced float4
    const int sr = tid >> 2;
    const int sk = (tid & 3) << 2;
    // compute map: 4x4 microtile
    const int tm = ((tid >> 4) & 15) << 2;  // 0..60
    const int tn = (tid & 15) << 2;         // 0..60

    const bool aok = (row0 + sr) < M;
    const float* aptr = A  + (size_t)(row0 + sr) * K + sk;
    const float* bptr = Bm + (size_t)(col0 + sr) * K + sk;

    float4 acc[4];
#pragma unroll
    for (int i = 0; i < 4; i++) acc[i] = make_float4(0.f, 0.f, 0.f, 0.f);

    // prefetch tile 0
    float4 pa = make_float4(0.f, 0.f, 0.f, 0.f);
    float4 pb;
    if (aok) pa = *(const float4*)aptr;
    pb = *(const float4*)bptr;

    int buf = 0;
    for (int kb = 0; kb < K; kb += BK) {
        // commit prefetched regs to LDS[buf]
        As[buf][sk + 0][sr] = pa.x; As[buf][sk + 1][sr] = pa.y;
        As[buf][sk + 2][sr] = pa.z; As[buf][sk + 3][sr] = pa.w;
        Bs[buf][sk + 0][sr] = pb.x; Bs[buf][sk + 1][sr] = pb.y;
        Bs[buf][sk + 2][sr] = pb.z; Bs[buf][sk + 3][sr] = pb.w;
        __syncthreads();   // single barrier per K-step (write->read hand-off;
                           // next iter writes the OTHER buffer, ordered by this barrier)

        // issue next tile's global loads; latency hidden under compute below
        if (kb + BK < K) {
            if (aok) pa = *(const float4*)(aptr + kb + BK);
            pb = *(const float4*)(bptr + kb + BK);
        }

#pragma unroll
        for (int k = 0; k < BK; ++k) {
            const float4 av = *(const float4*)&As[buf][k][tm];
            const float4 bv = *(const float4*)&Bs[buf][k][tn];
            OUTER(acc[0], bv, av.x);
            OUTER(acc[1], bv, av.y);
            OUTER(acc[2], bv, av.z);
            OUTER(acc[3], bv, av.w);
        }
        buf ^= 1;
    }

    // --- epilogue: bias, optional mask zero, vectorized store ---
    const float4 bv = *(const float4*)(bias + col0 + tn);
#pragma unroll
    for (int i = 0; i < 4; i++) {
        const int row = row0 + tm + i;
        if (row >= M) continue;
        float4 o = acc[i];
        o.x += bv.x; o.y += bv.y; o.z += bv.z; o.w += bv.w;
        if (maskp && maskp[row]) o = make_float4(0.f, 0.f, 0.f, 0.f);
        *(float4*)(C + (size_t)row * N + col0 + tn) = o;
    }
}

// ---------------------------------------------------------------------------
// Box-attention sampling, two-phase:
//   phase 1 (128 threads): 4 rows x 8 heads x 4 levels -> clamped indices +
//            combined weights (softmax * bilinear * validity) into LDS
//   phase 2 (256 threads): pure gather+FMA; 8 float4-lanes x 8 heads x 4 rows
//   unroll 8 (was 4): 32 gathers in flight vs 16; VGPR=28 had headroom.
// ---------------------------------------------------------------------------
#define ROWS 4
#define PP 17   // padded point dim

__global__ __launch_bounds__(256) void box_sample(
    const float* __restrict__ v,      // (B*L2, 256) projected+masked value
    const float* __restrict__ alog,   // (B*L1, 128) attn logits (h,l,p)
    const float* __restrict__ blg,    // (B*L1, 128) box logits (h,l,4)
    const float* __restrict__ rwin,   // (B*L1, 4)
    const float* __restrict__ vratio, // (B, NLEVEL, 2)
    float* __restrict__ outp,         // (B*L1, 256)
    int M1, int L1, int L2)
{
    __shared__ int   s_idx[ROWS][NHEAD][PP][4];
    __shared__ float s_w  [ROWS][NHEAD][PP][4];

    const int row0 = blockIdx.x * ROWS;
    const int tid  = threadIdx.x;

    // ================= phase 1 =================
    if (tid < 128) {
        const int l = tid & 3;
        const int h = (tid >> 2) & 7;
        const int r = tid >> 5;             // 0..3
        const int rowq = row0 + r;
        if (rowq < M1) {
            const int b = (rowq >= L1) ? 1 : 0;
            float la[16];
            const float* al = alog + (size_t)rowq * 128 + h * 16;
            {
                const float4 q0 = *(const float4*)(al + 0);
                const float4 q1 = *(const float4*)(al + 4);
                const float4 q2 = *(const float4*)(al + 8);
                const float4 q3 = *(const float4*)(al + 12);
                la[0]=q0.x; la[1]=q0.y; la[2]=q0.z; la[3]=q0.w;
                la[4]=q1.x; la[5]=q1.y; la[6]=q1.z; la[7]=q1.w;
                la[8]=q2.x; la[9]=q2.y; la[10]=q2.z; la[11]=q2.w;
                la[12]=q3.x; la[13]=q3.y; la[14]=q3.z; la[15]=q3.w;
            }
            float m = la[0];
#pragma unroll
            for (int i = 1; i < 16; i++) m = fmaxf(m, la[i]);
            float s = 0.f;
#pragma unroll
            for (int i = 0; i < 16; i++) { la[i] = __expf(la[i] - m); s += la[i]; }
            const float inv = 1.f / s;

            const int H  = (l == 0) ? 76 : (l == 1) ? 38 : (l == 2) ? 19 : 10;
            const int W  = H;
            const int s0 = (l == 0) ? 0  : (l == 1) ? 5776 : (l == 2) ? 7220 : 7581;

            const float4 ob = *(const float4*)(blg + (size_t)rowq * 128 + h * 16 + l * 4);
            const float4 rw = *(const float4*)(rwin + (size_t)rowq * 4);
            const float vrx = vratio[(b * NLEVEL + l) * 2 + 0];
            const float vry = vratio[(b * NLEVEL + l) * 2 + 1];

            const float cx = rw.x + ob.x * 0.125f * rw.z;
            const float cy = rw.y + ob.y * 0.125f * rw.w;
            const float sw = fmaxf(rw.z + ob.z * 0.125f * rw.z, 0.f);
            const float sh = fmaxf(rw.w + ob.w * 0.125f * rw.w, 0.f);

            const int vbase = (b * L2 + s0) * DMODEL + h * HDIM;

#pragma unroll
            for (int p = 0; p < 4; ++p) {
                const float kx = (p & 1)  ? 0.25f : -0.25f;
                const float ky = (p >> 1) ? 0.25f : -0.25f;
                const float gx = (cx + kx * sw) * vrx;
                const float gy = (cy + ky * sh) * vry;
                const float x = gx * (float)W - 0.5f;
                const float y = gy * (float)H - 0.5f;
                const float x0f = floorf(x);
                const float y0f = floorf(y);
                const float lx = x - x0f, ly = y - y0f;
                const int x0 = (int)x0f, y0 = (int)y0f;
                const float aw = la[l * 4 + p] * inv;
                const float wb[4] = { (1.f - ly) * (1.f - lx) * aw,
                                      (1.f - ly) * lx * aw,
                                      ly * (1.f - lx) * aw,
                                      ly * lx * aw };
                const int lp = l * 4 + p;
#pragma unroll
                for (int j = 0; j < 4; ++j) {
                    const int yy = y0 + (j >> 1);
                    const int xx = x0 + (j & 1);
                    const bool ok = (yy >= 0) & (yy < H) & (xx >= 0) & (xx < W);
                    const int yc = min(max(yy, 0), H - 1);
                    const int xc = min(max(xx, 0), W - 1);
                    s_idx[r][h][lp][j] = vbase + (yc * W + xc) * DMODEL;
                    s_w  [r][h][lp][j] = ok ? wb[j] : 0.f;
                }
            }
        }
    }
    __syncthreads();

    // ================= phase 2 =================
    {
        const int c4 = (tid & 7) << 2;      // channel quad: 0..28
        const int h  = (tid >> 3) & 7;
        const int r  = tid >> 6;            // 0..3
        const int rowq = row0 + r;
        if (rowq < M1) {
            float4 acc = make_float4(0.f, 0.f, 0.f, 0.f);
#pragma unroll 8
            for (int p = 0; p < 16; ++p) {
                const int4   iv = *(const int4  *)&s_idx[r][h][p][0];
                const float4 wv = *(const float4*)&s_w  [r][h][p][0];
                const float4 g0 = *(const float4*)(v + iv.x + c4);
                const float4 g1 = *(const float4*)(v + iv.y + c4);
                const float4 g2 = *(const float4*)(v + iv.z + c4);
                const float4 g3 = *(const float4*)(v + iv.w + c4);
                acc.x += wv.x*g0.x; acc.y += wv.x*g0.y; acc.z += wv.x*g0.z; acc.w += wv.x*g0.w;
                acc.x += wv.y*g1.x; acc.y += wv.y*g1.y; acc.z += wv.y*g1.z; acc.w += wv.y*g1.w;
                acc.x += wv.z*g2.x; acc.y += wv.z*g2.y; acc.z += wv.z*g2.z; acc.w += wv.z*g2.w;
                acc.x += wv.w*g3.x; acc.y += wv.w*g3.y; acc.z += wv.w*g3.z; acc.w += wv.w*g3.w;
            }
            *(float4*)(outp + (size_t)rowq * DMODEL + h * HDIM + c4) = acc;
        }
    }
}

// ---------------------------------------------------------------------------
extern "C" void kernel_launch(void* const* d_in, const int* in_sizes, int n_in,
                              void* d_out, int out_size, void* d_ws, size_t ws_size,
                              hipStream_t stream) {
    const float* query   = (const float*)d_in[0];
    const float* value   = (const float*)d_in[1];
    const unsigned char* v_mask = (const unsigned char*)d_in[3];
    const float* v_valid = (const float*)d_in[5];
    const float* ref_win = (const float*)d_in[6];
    const float* vproj_w = (const float*)d_in[7];
    const float* vproj_b = (const float*)d_in[8];
    const float* oproj_w = (const float*)d_in[9];
    const float* oproj_b = (const float*)d_in[10];
    const float* box_w   = (const float*)d_in[11];
    const float* box_b   = (const float*)d_in[12];
    const float* attn_w  = (const float*)d_in[13];
    const float* attn_b  = (const float*)d_in[14];

    const int B  = 2;
    const int M1 = in_sizes[0] / DMODEL;   // B*L1
    const int M2 = in_sizes[1] / DMODEL;   // B*L2
    const int L1 = M1 / B;
    const int L2 = M2 / B;

    float* ws    = (float*)d_ws;
    float* vproj = ws;                                  // M2*256
    float* alog  = vproj + (size_t)M2 * DMODEL;         // M1*128
    float* blg   = alog  + (size_t)M1 * 128;            // M1*128
    float* outp  = blg   + (size_t)M1 * 128;            // M1*256

    const dim3 blk(256);
    const int mb1 = (M1 + 63) / 64;
    const int mb2 = (M2 + 63) / 64;

    // 1) value projection (+mask zeroing fused)
    gemm_bt<0><<<dim3(4, mb2, 1), blk, 0, stream>>>(
        value, vproj_w, vproj_b, vproj, vproj_w, vproj_b, vproj,
        v_mask, M2, DMODEL, DMODEL);

    // 2) attn + box logits in one launch (blockIdx.z selects the set)
    gemm_bt<1><<<dim3(2, mb1, 2), blk, 0, stream>>>(
        query, attn_w, attn_b, alog, box_w, box_b, blg,
        nullptr, M1, 128, DMODEL);

    // 3) sampling
    box_sample<<<dim3((M1 + ROWS - 1) / ROWS), blk, 0, stream>>>(
        vproj, alog, blg, ref_win, v_valid, outp, M1, L1, L2);

    // 4) output projection
    gemm_bt<2><<<dim3(4, mb1, 1), blk, 0, stream>>>(
        outp, oproj_w, oproj_b, (float*)d_out, oproj_w, oproj_b, (float*)d_out,
        nullptr, M1, DMODEL, DMODEL);
}

// Round 8
// 128.390 us; speedup vs baseline: 1.4820x; 1.2107x over previous
//
#include <hip/hip_runtime.h>
#include <cstdint>
#include <cstddef>

#define NHEAD 8
#define HDIM 32
#define DMODEL 256
#define NLEVEL 4
#define NPOINT 4

using short8 = __attribute__((ext_vector_type(8))) short;
using f32x4  = __attribute__((ext_vector_type(4))) float;

// ---- bf16 helpers (RNE), bit-level to avoid type quirks --------------------
__device__ __forceinline__ unsigned short f2bf(float x) {
    unsigned int b = __float_as_uint(x);
    unsigned int r = b + 0x7FFFu + ((b >> 16) & 1u);
    return (unsigned short)(r >> 16);
}
__device__ __forceinline__ float bf2f(unsigned short u) {
    return __uint_as_float(((unsigned int)u) << 16);
}

// ---------------------------------------------------------------------------
// convsplit: (rows,256) f32 -> (rows,512) bf16 as [hi(256) | lo(256)] per row
// ---------------------------------------------------------------------------
__global__ __launch_bounds__(256) void convsplit(
    const float* __restrict__ in, unsigned short* __restrict__ out, int rows)
{
    const int idx = blockIdx.x * 256 + threadIdx.x;   // one thread = 4 elems
    if (idx >= rows * 64) return;
    const int r = idx >> 6, c = (idx & 63) << 2;
    const float4 v = *(const float4*)(in + (size_t)r * 256 + c);
    ushort4 hi, lo;
    hi.x = f2bf(v.x); lo.x = f2bf(v.x - bf2f(hi.x));
    hi.y = f2bf(v.y); lo.y = f2bf(v.y - bf2f(hi.y));
    hi.z = f2bf(v.z); lo.z = f2bf(v.z - bf2f(hi.z));
    hi.w = f2bf(v.w); lo.w = f2bf(v.w - bf2f(hi.w));
    *(ushort4*)(out + (size_t)r * 512 + c)       = hi;
    *(ushort4*)(out + (size_t)r * 512 + 256 + c) = lo;
}

// convw: all four weight matrices in one launch (blockIdx.y selects source)
__global__ __launch_bounds__(256) void convw(
    const float* __restrict__ w0, const float* __restrict__ w1,
    const float* __restrict__ w2, const float* __restrict__ w3,
    unsigned short* __restrict__ b0, unsigned short* __restrict__ b1,
    unsigned short* __restrict__ blg)
{
    const int y = blockIdx.y;
    const float* src = (y == 0) ? w0 : (y == 1) ? w1 : (y == 2) ? w2 : w3;
    unsigned short* dst = (y == 0) ? b0 : (y == 1) ? b1 : (y == 2) ? blg : (blg + 128 * 512);
    const int rows = (y < 2) ? 256 : 128;
    const int idx = blockIdx.x * 256 + threadIdx.x;
    if (idx >= rows * 64) return;
    const int r = idx >> 6, c = (idx & 63) << 2;
    const float4 v = *(const float4*)(src + (size_t)r * 256 + c);
    ushort4 hi, lo;
    hi.x = f2bf(v.x); lo.x = f2bf(v.x - bf2f(hi.x));
    hi.y = f2bf(v.y); lo.y = f2bf(v.y - bf2f(hi.y));
    hi.z = f2bf(v.z); lo.z = f2bf(v.z - bf2f(hi.z));
    hi.w = f2bf(v.w); lo.w = f2bf(v.w - bf2f(hi.w));
    *(ushort4*)(dst + (size_t)r * 512 + c)       = hi;
    *(ushort4*)(dst + (size_t)r * 512 + 256 + c) = lo;
}

// ---------------------------------------------------------------------------
// Split-bf16 MFMA GEMM: C(M,256) f32 = A(M,K=256) @ W(256,K)^T via K'=768:
//   segments: A-side [hi,hi,lo], B-side [hi,lo,hi]  (C = AhBh + AhBl + AlBh)
// A/B stored as (rows,512) bf16 [hi|lo]; segment remap is pure addressing.
// 64x64 tile, BK=128 (6 K-steps), 4 waves each 32x32 (2x2 16x16x32 frags).
// LDS XOR-swizzle: phys16Bslot = logical ^ (row&7)  (G4: row-major 256B rows
// would be a 16-way bank conflict on ds_read_b128).
// ---------------------------------------------------------------------------
__global__ __launch_bounds__(256) void gemm_mfma(
    const unsigned short* __restrict__ Abf,  // (M,512)
    const unsigned short* __restrict__ Bbf,  // (256,512)
    const float* __restrict__ biasA, const float* __restrict__ biasB, int bsplit,
    const unsigned char* __restrict__ maskp,
    float* __restrict__ C, int M)
{
    __shared__ __align__(16) unsigned short As[64 * 128];
    __shared__ __align__(16) unsigned short Bs[64 * 128];

    const int tid  = threadIdx.x;
    const int lane = tid & 63;
    const int wave = tid >> 6;
    const int wm = wave >> 1, wn = wave & 1;
    const int lr = lane & 15, lg = lane >> 4;

    const int row0 = blockIdx.y * 64;
    const int col0 = blockIdx.x * 64;

    // staging map: thread -> rows {srow, +16, +32, +48}, phys slot skbp (0..15)
    const int srow = tid >> 4;
    const int skbp = tid & 15;
    const int skbl = skbp ^ (srow & 7);      // logical slot (bit3 passes through)

    const unsigned short* pA0 = Abf + (size_t)min(row0 + srow,      M - 1) * 512 + skbl * 8;
    const unsigned short* pA1 = Abf + (size_t)min(row0 + srow + 16, M - 1) * 512 + skbl * 8;
    const unsigned short* pA2 = Abf + (size_t)min(row0 + srow + 32, M - 1) * 512 + skbl * 8;
    const unsigned short* pA3 = Abf + (size_t)min(row0 + srow + 48, M - 1) * 512 + skbl * 8;
    const unsigned short* pB0 = Bbf + (size_t)(col0 + srow)      * 512 + skbl * 8;
    const unsigned short* pB1 = Bbf + (size_t)(col0 + srow + 16) * 512 + skbl * 8;
    const unsigned short* pB2 = Bbf + (size_t)(col0 + srow + 32) * 512 + skbl * 8;
    const unsigned short* pB3 = Bbf + (size_t)(col0 + srow + 48) * 512 + skbl * 8;

    const int dst = srow * 128 + skbp * 8;   // ushort units; +i*2048 per row group

    f32x4 acc00 = {0.f, 0.f, 0.f, 0.f}, acc01 = acc00, acc10 = acc00, acc11 = acc00;

    // prefetch step 0 (seg 0: baseA = baseB = 0)
    uint4 va0 = *(const uint4*)pA0, va1 = *(const uint4*)pA1;
    uint4 va2 = *(const uint4*)pA2, va3 = *(const uint4*)pA3;
    uint4 vb0 = *(const uint4*)pB0, vb1 = *(const uint4*)pB1;
    uint4 vb2 = *(const uint4*)pB2, vb3 = *(const uint4*)pB3;

    const int ra = wm * 32 + lr;    // a-frag rows: ra, ra+16
    const int cb = wn * 32 + lr;    // b-frag cols: cb, cb+16
    const int xr = lr & 7;          // read-side swizzle key

    for (int st = 0; st < 6; ++st) {
        if (st) __syncthreads();
        *(uint4*)&As[dst        ] = va0;
        *(uint4*)&As[dst + 2048 ] = va1;
        *(uint4*)&As[dst + 4096 ] = va2;
        *(uint4*)&As[dst + 6144 ] = va3;
        *(uint4*)&Bs[dst        ] = vb0;
        *(uint4*)&Bs[dst + 2048 ] = vb1;
        *(uint4*)&Bs[dst + 4096 ] = vb2;
        *(uint4*)&Bs[dst + 6144 ] = vb3;
        __syncthreads();

        if (st < 5) {
            const int sn  = st + 1;
            const int seg = sn >> 1;
            const int ksb = (sn & 1) * 16;
            const int bA  = ((seg < 2)  ? ksb : 32 + ksb) * 8;  // A: [hi,hi,lo]
            const int bB  = ((seg == 1) ? 32 + ksb : ksb) * 8;  // B: [hi,lo,hi]
            va0 = *(const uint4*)(pA0 + bA); va1 = *(const uint4*)(pA1 + bA);
            va2 = *(const uint4*)(pA2 + bA); va3 = *(const uint4*)(pA3 + bA);
            vb0 = *(const uint4*)(pB0 + bB); vb1 = *(const uint4*)(pB1 + bB);
            vb2 = *(const uint4*)(pB2 + bB); vb3 = *(const uint4*)(pB3 + bB);
        }

#pragma unroll
        for (int kf = 0; kf < 4; ++kf) {
            const int kbp = (kf * 4 + lg) ^ xr;
            const short8 a0 = *(const short8*)&As[ ra       * 128 + kbp * 8];
            const short8 a1 = *(const short8*)&As[(ra + 16) * 128 + kbp * 8];
            const short8 b0 = *(const short8*)&Bs[ cb       * 128 + kbp * 8];
            const short8 b1 = *(const short8*)&Bs[(cb + 16) * 128 + kbp * 8];
            acc00 = __builtin_amdgcn_mfma_f32_16x16x32_bf16(a0, b0, acc00, 0, 0, 0);
            acc01 = __builtin_amdgcn_mfma_f32_16x16x32_bf16(a0, b1, acc01, 0, 0, 0);
            acc10 = __builtin_amdgcn_mfma_f32_16x16x32_bf16(a1, b0, acc10, 0, 0, 0);
            acc11 = __builtin_amdgcn_mfma_f32_16x16x32_bf16(a1, b1, acc11, 0, 0, 0);
        }
    }

    // epilogue: C/D layout col=lane&15, row=(lane>>4)*4+j  [m89-verified]
#pragma unroll
    for (int m = 0; m < 2; ++m) {
#pragma unroll
        for (int n = 0; n < 2; ++n) {
            const f32x4 av = (m == 0) ? (n == 0 ? acc00 : acc01)
                                      : (n == 0 ? acc10 : acc11);
            const int colg = col0 + wn * 32 + n * 16 + lr;
            const float bias = (colg < bsplit) ? biasA[colg] : biasB[colg - bsplit];
#pragma unroll
            for (int j = 0; j < 4; ++j) {
                const int rowg = row0 + wm * 32 + m * 16 + lg * 4 + j;
                if (rowg < M) {
                    float o = av[j] + bias;
                    if (maskp && maskp[rowg]) o = 0.f;
                    C[(size_t)rowg * 256 + colg] = o;
                }
            }
        }
    }
}

// ---------------------------------------------------------------------------
// f32 GEMM fallback (R6, proven): used only if ws_size too small for MFMA path
// ---------------------------------------------------------------------------
#define OUTER(ACC, BV, a) { (ACC).x += (a)*(BV).x; (ACC).y += (a)*(BV).y; \
                            (ACC).z += (a)*(BV).z; (ACC).w += (a)*(BV).w; }

template<int ID>
__global__ __launch_bounds__(256) void gemm_bt(
    const float* __restrict__ A,
    const float* __restrict__ B0, const float* __restrict__ bias0, float* __restrict__ C0,
    const float* __restrict__ B1, const float* __restrict__ bias1, float* __restrict__ C1,
    const unsigned char* __restrict__ maskp,
    int M, int N, int K)
{
    constexpr int BM = 64, BN = 64, BK = 16;
    __shared__ float As[2][BK][BM];
    __shared__ float Bs[2][BK][BN];

    const float* Bm   = blockIdx.z ? B1 : B0;
    const float* bias = blockIdx.z ? bias1 : bias0;
    float*       C    = blockIdx.z ? C1 : C0;

    const int row0 = blockIdx.y * BM;
    const int col0 = blockIdx.x * BN;
    const int tid  = threadIdx.x;
    const int sr = tid >> 2;
    const int sk = (tid & 3) << 2;
    const int tm = ((tid >> 4) & 15) << 2;
    const int tn = (tid & 15) << 2;

    const bool aok = (row0 + sr) < M;
    const float* aptr = A  + (size_t)(row0 + sr) * K + sk;
    const float* bptr = Bm + (size_t)(col0 + sr) * K + sk;

    float4 acc[4];
#pragma unroll
    for (int i = 0; i < 4; i++) acc[i] = make_float4(0.f, 0.f, 0.f, 0.f);

    float4 pa = make_float4(0.f, 0.f, 0.f, 0.f);
    float4 pb;
    if (aok) pa = *(const float4*)aptr;
    pb = *(const float4*)bptr;

    int buf = 0;
    for (int kb = 0; kb < K; kb += BK) {
        As[buf][sk + 0][sr] = pa.x; As[buf][sk + 1][sr] = pa.y;
        As[buf][sk + 2][sr] = pa.z; As[buf][sk + 3][sr] = pa.w;
        Bs[buf][sk + 0][sr] = pb.x; Bs[buf][sk + 1][sr] = pb.y;
        Bs[buf][sk + 2][sr] = pb.z; Bs[buf][sk + 3][sr] = pb.w;
        __syncthreads();
        if (kb + BK < K) {
            if (aok) pa = *(const float4*)(aptr + kb + BK);
            pb = *(const float4*)(bptr + kb + BK);
        }
#pragma unroll
        for (int k = 0; k < BK; ++k) {
            const float4 av = *(const float4*)&As[buf][k][tm];
            const float4 bv = *(const float4*)&Bs[buf][k][tn];
            OUTER(acc[0], bv, av.x);
            OUTER(acc[1], bv, av.y);
            OUTER(acc[2], bv, av.z);
            OUTER(acc[3], bv, av.w);
        }
        buf ^= 1;
    }
    const float4 bv = *(const float4*)(bias + col0 + tn);
#pragma unroll
    for (int i = 0; i < 4; i++) {
        const int row = row0 + tm + i;
        if (row >= M) continue;
        float4 o = acc[i];
        o.x += bv.x; o.y += bv.y; o.z += bv.z; o.w += bv.w;
        if (maskp && maskp[row]) o = make_float4(0.f, 0.f, 0.f, 0.f);
        *(float4*)(C + (size_t)row * N + col0 + tn) = o;
    }
}

// ---------------------------------------------------------------------------
// Box-attention sampling (two-phase, R4-proven). OBF=0: f32 out (M1,256);
// OBF=1: split-bf16 out (M1,512) [hi|lo] for direct MFMA-GEMM consumption.
// Logits given as two pointers + row stride (supports combined M1x256 layout).
// ---------------------------------------------------------------------------
#define ROWS 4
#define PP 17

template<int OBF>
__global__ __launch_bounds__(256) void box_sample(
    const float* __restrict__ v,
    const float* __restrict__ alogp, const float* __restrict__ blgp, int lstride,
    const float* __restrict__ rwin,
    const float* __restrict__ vratio,
    void* __restrict__ outp,
    int M1, int L1, int L2)
{
    __shared__ int   s_idx[ROWS][NHEAD][PP][4];
    __shared__ float s_w  [ROWS][NHEAD][PP][4];

    const int row0 = blockIdx.x * ROWS;
    const int tid  = threadIdx.x;

    if (tid < 128) {
        const int l = tid & 3;
        const int hh = (tid >> 2) & 7;
        const int r = tid >> 5;
        const int rowq = row0 + r;
        if (rowq < M1) {
            const int b = (rowq >= L1) ? 1 : 0;
            float la[16];
            const float* al = alogp + (size_t)rowq * lstride + hh * 16;
            {
                const float4 q0 = *(const float4*)(al + 0);
                const float4 q1 = *(const float4*)(al + 4);
                const float4 q2 = *(const float4*)(al + 8);
                const float4 q3 = *(const float4*)(al + 12);
                la[0]=q0.x; la[1]=q0.y; la[2]=q0.z; la[3]=q0.w;
                la[4]=q1.x; la[5]=q1.y; la[6]=q1.z; la[7]=q1.w;
                la[8]=q2.x; la[9]=q2.y; la[10]=q2.z; la[11]=q2.w;
                la[12]=q3.x; la[13]=q3.y; la[14]=q3.z; la[15]=q3.w;
            }
            float m = la[0];
#pragma unroll
            for (int i = 1; i < 16; i++) m = fmaxf(m, la[i]);
            float s = 0.f;
#pragma unroll
            for (int i = 0; i < 16; i++) { la[i] = __expf(la[i] - m); s += la[i]; }
            const float inv = 1.f / s;

            const int H  = (l == 0) ? 76 : (l == 1) ? 38 : (l == 2) ? 19 : 10;
            const int W  = H;
            const int s0 = (l == 0) ? 0  : (l == 1) ? 5776 : (l == 2) ? 7220 : 7581;

            const float4 ob = *(const float4*)(blgp + (size_t)rowq * lstride + hh * 16 + l * 4);
            const float4 rw = *(const float4*)(rwin + (size_t)rowq * 4);
            const float vrx = vratio[(b * NLEVEL + l) * 2 + 0];
            const float vry = vratio[(b * NLEVEL + l) * 2 + 1];

            const float cx = rw.x + ob.x * 0.125f * rw.z;
            const float cy = rw.y + ob.y * 0.125f * rw.w;
            const float sw = fmaxf(rw.z + ob.z * 0.125f * rw.z, 0.f);
            const float sh = fmaxf(rw.w + ob.w * 0.125f * rw.w, 0.f);

            const int vbase = (b * L2 + s0) * DMODEL + hh * HDIM;

#pragma unroll
            for (int p = 0; p < 4; ++p) {
                const float kx = (p & 1)  ? 0.25f : -0.25f;
                const float ky = (p >> 1) ? 0.25f : -0.25f;
                const float gx = (cx + kx * sw) * vrx;
                const float gy = (cy + ky * sh) * vry;
                const float x = gx * (float)W - 0.5f;
                const float y = gy * (float)H - 0.5f;
                const float x0f = floorf(x);
                const float y0f = floorf(y);
                const float lx = x - x0f, ly = y - y0f;
                const int x0 = (int)x0f, y0 = (int)y0f;
                const float aw = la[l * 4 + p] * inv;
                const float wb[4] = { (1.f - ly) * (1.f - lx) * aw,
                                      (1.f - ly) * lx * aw,
                                      ly * (1.f - lx) * aw,
                                      ly * lx * aw };
                const int lp = l * 4 + p;
#pragma unroll
                for (int j = 0; j < 4; ++j) {
                    const int yy = y0 + (j >> 1);
                    const int xx = x0 + (j & 1);
                    const bool ok = (yy >= 0) & (yy < H) & (xx >= 0) & (xx < W);
                    const int yc = min(max(yy, 0), H - 1);
                    const int xc = min(max(xx, 0), W - 1);
                    s_idx[r][hh][lp][j] = vbase + (yc * W + xc) * DMODEL;
                    s_w  [r][hh][lp][j] = ok ? wb[j] : 0.f;
                }
            }
        }
    }
    __syncthreads();

    {
        const int c4 = (tid & 7) << 2;
        const int hh = (tid >> 3) & 7;
        const int r  = tid >> 6;
        const int rowq = row0 + r;
        if (rowq < M1) {
            float4 acc = make_float4(0.f, 0.f, 0.f, 0.f);
#pragma unroll 8
            for (int p = 0; p < 16; ++p) {
                const int4   iv = *(const int4  *)&s_idx[r][hh][p][0];
                const float4 wv = *(const float4*)&s_w  [r][hh][p][0];
                const float4 g0 = *(const float4*)(v + iv.x + c4);
                const float4 g1 = *(const float4*)(v + iv.y + c4);
                const float4 g2 = *(const float4*)(v + iv.z + c4);
                const float4 g3 = *(const float4*)(v + iv.w + c4);
                acc.x += wv.x*g0.x; acc.y += wv.x*g0.y; acc.z += wv.x*g0.z; acc.w += wv.x*g0.w;
                acc.x += wv.y*g1.x; acc.y += wv.y*g1.y; acc.z += wv.y*g1.z; acc.w += wv.y*g1.w;
                acc.x += wv.z*g2.x; acc.y += wv.z*g2.y; acc.z += wv.z*g2.z; acc.w += wv.z*g2.w;
                acc.x += wv.w*g3.x; acc.y += wv.w*g3.y; acc.z += wv.w*g3.z; acc.w += wv.w*g3.w;
            }
            if (OBF == 0) {
                *(float4*)((float*)outp + (size_t)rowq * DMODEL + hh * HDIM + c4) = acc;
            } else {
                unsigned short* ob = (unsigned short*)outp;
                ushort4 hi, lo;
                hi.x = f2bf(acc.x); lo.x = f2bf(acc.x - bf2f(hi.x));
                hi.y = f2bf(acc.y); lo.y = f2bf(acc.y - bf2f(hi.y));
                hi.z = f2bf(acc.z); lo.z = f2bf(acc.z - bf2f(hi.z));
                hi.w = f2bf(acc.w); lo.w = f2bf(acc.w - bf2f(hi.w));
                *(ushort4*)(ob + (size_t)rowq * 512 + hh * HDIM + c4)       = hi;
                *(ushort4*)(ob + (size_t)rowq * 512 + 256 + hh * HDIM + c4) = lo;
            }
        }
    }
}

// ---------------------------------------------------------------------------
extern "C" void kernel_launch(void* const* d_in, const int* in_sizes, int n_in,
                              void* d_out, int out_size, void* d_ws, size_t ws_size,
                              hipStream_t stream) {
    const float* query   = (const float*)d_in[0];
    const float* value   = (const float*)d_in[1];
    const unsigned char* v_mask = (const unsigned char*)d_in[3];
    const float* v_valid = (const float*)d_in[5];
    const float* ref_win = (const float*)d_in[6];
    const float* vproj_w = (const float*)d_in[7];
    const float* vproj_b = (const float*)d_in[8];
    const float* oproj_w = (const float*)d_in[9];
    const float* oproj_b = (const float*)d_in[10];
    const float* box_w   = (const float*)d_in[11];
    const float* box_b   = (const float*)d_in[12];
    const float* attn_w  = (const float*)d_in[13];
    const float* attn_b  = (const float*)d_in[14];

    const int B  = 2;
    const int M1 = in_sizes[0] / DMODEL;   // B*L1
    const int M2 = in_sizes[1] / DMODEL;   // B*L2
    const int L1 = M1 / B;
    const int L2 = M2 / B;
    const dim3 blk(256);

    // --- workspace plan (lifetime-shared): R1 = Av then lgt; R2 = Aq then outp'
    const size_t szAv  = (size_t)M2 * 512 * 2;
    const size_t szAq  = (size_t)M1 * 512 * 2;
    const size_t szLgt = (size_t)M1 * 256 * 4;
    const size_t szVp  = (size_t)M2 * 256 * 4;
    const size_t szB   = 3 * 256 * 512 * 2;
    const size_t r1 = (szAv > szLgt ? szAv : szLgt);
    const size_t r2 = szAq;  // == outp' size (M1*512*2 == M1*256*4)
    const size_t need = r1 + r2 + szVp + szB;

    char* wsb = (char*)d_ws;

    if (ws_size >= need) {
        // ================= split-bf16 MFMA path =================
        unsigned short* Av   = (unsigned short*)(wsb);            // R1 early
        float*          lgt  = (float*)(wsb);                     // R1 late
        unsigned short* Aq   = (unsigned short*)(wsb + r1);       // R2 early
        unsigned short* Obf  = (unsigned short*)(wsb + r1);       // (unused alias)
        unsigned short* OutS = (unsigned short*)(wsb + r1);       // R2 late
        float*          vprj = (float*)(wsb + r1 + r2);
        unsigned short* Bv   = (unsigned short*)(wsb + r1 + r2 + szVp);
        unsigned short* Bo   = Bv  + 256 * 512;
        unsigned short* Blg  = Bo  + 256 * 512;
        (void)Obf;

        convsplit<<<dim3((M2 * 64 + 255) / 256), blk, 0, stream>>>(value, Av, M2);
        convsplit<<<dim3((M1 * 64 + 255) / 256), blk, 0, stream>>>(query, Aq, M1);
        convw<<<dim3(64, 4), blk, 0, stream>>>(vproj_w, oproj_w, attn_w, box_w, Bv, Bo, Blg);

        // value projection (+mask)
        gemm_mfma<<<dim3(4, (M2 + 63) / 64), blk, 0, stream>>>(
            Av, Bv, vproj_b, vproj_b, 256, v_mask, vprj, M2);
        // combined logits: C cols [0,128)=attn, [128,256)=box (lgt overwrites Av region)
        gemm_mfma<<<dim3(4, (M1 + 63) / 64), blk, 0, stream>>>(
            Aq, Blg, attn_b, box_b, 128, nullptr, lgt, M1);
        // sampling -> split-bf16 output (overwrites Aq region)
        box_sample<1><<<dim3((M1 + ROWS - 1) / ROWS), blk, 0, stream>>>(
            vprj, lgt, lgt + 128, 256, ref_win, v_valid, (void*)OutS, M1, L1, L2);
        // output projection
        gemm_mfma<<<dim3(4, (M1 + 63) / 64), blk, 0, stream>>>(
            OutS, Bo, oproj_b, oproj_b, 256, nullptr, (float*)d_out, M1);
    } else {
        // ================= f32 fallback (R6 path) =================
        float* vprj = (float*)wsb;                                // M2*256
        float* alog = vprj + (size_t)M2 * DMODEL;                 // M1*128
        float* blg  = alog + (size_t)M1 * 128;                    // M1*128
        float* outp = blg  + (size_t)M1 * 128;                    // M1*256

        const int mb1 = (M1 + 63) / 64;
        const int mb2 = (M2 + 63) / 64;

        gemm_bt<0><<<dim3(4, mb2, 1), blk, 0, stream>>>(
            value, vproj_w, vproj_b, vprj, vproj_w, vproj_b, vprj,
            v_mask, M2, DMODEL, DMODEL);
        gemm_bt<1><<<dim3(2, mb1, 2), blk, 0, stream>>>(
            query, attn_w, attn_b, alog, box_w, box_b, blg,
            nullptr, M1, 128, DMODEL);
        box_sample<0><<<dim3((M1 + ROWS - 1) / ROWS), blk, 0, stream>>>(
            vprj, alog, blg, 128, ref_win, v_valid, (void*)outp, M1, L1, L2);
        gemm_bt<2><<<dim3(4, mb1, 1), blk, 0, stream>>>(
            outp, oproj_w, oproj_b, (float*)d_out, oproj_w, oproj_b, (float*)d_out,
            nullptr, M1, DMODEL, DMODEL);
    }
}